// Round 2
// baseline (261.359 us; speedup 1.0000x reference)
//
#include <hip/hip_runtime.h>

// MLP: 4 -> 8 -> 16 -> 32 -> 16 -> 8 -> 4, Linear + ReLU after every layer.
// fp32 everywhere. One thread processes ROWS=2 rows so each (wave-uniform)
// weight load feeds 2 FMAs and accumulator chains double up for ILP.

#define DEV_INLINE __device__ __forceinline__

template <int IN, int OUT>
DEV_INLINE void layer2(const float* __restrict__ W, const float* __restrict__ b,
                       const float (&ha)[IN], const float (&hb)[IN],
                       float (&oa)[OUT], float (&ob)[OUT]) {
#pragma unroll
    for (int j = 0; j < OUT; ++j) {
        float aa = b[j];
        float ab = aa;
#pragma unroll
        for (int i = 0; i < IN; ++i) {
            const float w = W[i * OUT + j];   // wave-uniform address -> s_load
            aa = fmaf(ha[i], w, aa);
            ab = fmaf(hb[i], w, ab);
        }
        oa[j] = fmaxf(aa, 0.0f);   // ReLU (after every layer incl. last)
        ob[j] = fmaxf(ab, 0.0f);
    }
}

__global__ void __launch_bounds__(256)
mlp6_kernel(const float* __restrict__ x,
            const float* __restrict__ W1, const float* __restrict__ b1,
            const float* __restrict__ W2, const float* __restrict__ b2,
            const float* __restrict__ W3, const float* __restrict__ b3,
            const float* __restrict__ W4, const float* __restrict__ b4,
            const float* __restrict__ W5, const float* __restrict__ b5,
            const float* __restrict__ W6, const float* __restrict__ b6,
            float* __restrict__ out, int npairs) {
    const int t = blockIdx.x * blockDim.x + threadIdx.x;
    if (t >= npairs) return;

    const long r0 = (long)t * 2;

    // Load two input rows (4 floats each) as float4 — coalesced 16B/lane.
    const float4 xa = reinterpret_cast<const float4*>(x)[r0];
    const float4 xb = reinterpret_cast<const float4*>(x)[r0 + 1];

    float h0a[4] = {xa.x, xa.y, xa.z, xa.w};
    float h0b[4] = {xb.x, xb.y, xb.z, xb.w};

    float h1a[8], h1b[8];
    layer2<4, 8>(W1, b1, h0a, h0b, h1a, h1b);

    float h2a[16], h2b[16];
    layer2<8, 16>(W2, b2, h1a, h1b, h2a, h2b);

    float h3a[32], h3b[32];
    layer2<16, 32>(W3, b3, h2a, h2b, h3a, h3b);

    float h4a[16], h4b[16];
    layer2<32, 16>(W4, b4, h3a, h3b, h4a, h4b);

    float h5a[8], h5b[8];
    layer2<16, 8>(W5, b5, h4a, h4b, h5a, h5b);

    float h6a[4], h6b[4];
    layer2<8, 4>(W6, b6, h5a, h5b, h6a, h6b);

    reinterpret_cast<float4*>(out)[r0]     = make_float4(h6a[0], h6a[1], h6a[2], h6a[3]);
    reinterpret_cast<float4*>(out)[r0 + 1] = make_float4(h6b[0], h6b[1], h6b[2], h6b[3]);
}

extern "C" void kernel_launch(void* const* d_in, const int* in_sizes, int n_in,
                              void* d_out, int out_size, void* d_ws, size_t ws_size,
                              hipStream_t stream) {
    const float* x  = (const float*)d_in[0];
    const float* W1 = (const float*)d_in[1];
    const float* b1 = (const float*)d_in[2];
    const float* W2 = (const float*)d_in[3];
    const float* b2 = (const float*)d_in[4];
    const float* W3 = (const float*)d_in[5];
    const float* b3 = (const float*)d_in[6];
    const float* W4 = (const float*)d_in[7];
    const float* b4 = (const float*)d_in[8];
    const float* W5 = (const float*)d_in[9];
    const float* b5 = (const float*)d_in[10];
    const float* W6 = (const float*)d_in[11];
    const float* b6 = (const float*)d_in[12];
    float* out = (float*)d_out;

    const int nrows  = in_sizes[0] / 4;   // N = 4,000,000
    const int npairs = nrows / 2;         // 2 rows per thread

    const int block = 256;
    const int grid  = (npairs + block - 1) / block;

    mlp6_kernel<<<grid, block, 0, stream>>>(x, W1, b1, W2, b2, W3, b3,
                                            W4, b4, W5, b5, W6, b6,
                                            out, npairs);
}

// Round 3
// 197.362 us; speedup vs baseline: 1.3243x; 1.3243x over previous
//
#include <hip/hip_runtime.h>

// MLP 4->8->16->32->16->8->4, ReLU after every layer, N=4M rows.
// MFMA f16 pipeline: each wave processes two independent 16-row tiles per
// iteration entirely via v_mfma_f32_16x16x32_f16, staging activations as f16
// in per-wave-private LDS buffers (no __syncthreads needed).
//
// Layouts (guide-verified for gfx950 16x16x32):
//   A frag: lane l holds A[row=l&15][k=(l>>4)*8+j], j=0..7   (8 f16, 4 VGPRs)
//   B frag: lane l holds B[k=(l>>4)*8+j][col=l&15]
//   C/D   : lane l, reg r holds D[row=(l>>4)*4+r][col=l&15]  (m89-verified)
// Unused K/N slots are zeroed in BOTH A and B frags (NaN*0=NaN hazard).

typedef _Float16 f16x8 __attribute__((ext_vector_type(8)));
typedef _Float16 f16x4 __attribute__((ext_vector_type(4)));
typedef _Float16 f16x2 __attribute__((ext_vector_type(2)));
typedef float    f32x4 __attribute__((ext_vector_type(4)));

#define DEV __device__ __forceinline__

// Per-(wave,tile) LDS activation buffers (f16, row-major, odd-16B-granule
// strides so 16-lane b128 reads spread across all 8 LDS granule columns):
constexpr int TILE_BYTES = 2432;
constexpr int OFF_IN = 0;    constexpr int STR_IN = 8;   // F=4  (input)
constexpr int OFF_B1 = 128;  constexpr int STR_B1 = 16;  // F=8  (L1/L5 out)
constexpr int OFF_B2 = 384;  constexpr int STR_B2 = 48;  // F=16 (L2/L4 out)
constexpr int OFF_B3 = 1152; constexpr int STR_B3 = 80;  // F=32 (L3 out)
constexpr int SMEM_BYTES = TILE_BYTES * 2 * 4;           // 2 tiles x 4 waves

DEV f16x8 build_bfrag(const float* __restrict__ W, int IN, int OUT,
                      int coltile, int lane) {
  const int col = (lane & 15) + 16 * coltile;
  const int k0  = (lane >> 4) * 8;
  f16x8 r = {0, 0, 0, 0, 0, 0, 0, 0};
#pragma unroll
  for (int j = 0; j < 8; ++j) {
    const int k = k0 + j;
    float w = 0.0f;
    if (k < IN && col < OUT) w = W[k * OUT + col];
    r[j] = (_Float16)w;   // RNE
  }
  return r;
}

template <int IN>
DEV f16x8 readA(const char* tb, int lane) {
  const int row = lane & 15;
  const int g   = lane >> 4;
  f16x8 a = {0, 0, 0, 0, 0, 0, 0, 0};
  if constexpr (IN == 4) {
    if (g == 0) {
      f16x4 t = *(const f16x4*)(tb + OFF_IN + row * STR_IN);
      a[0] = t[0]; a[1] = t[1]; a[2] = t[2]; a[3] = t[3];
    }
  } else if constexpr (IN == 8) {
    if (g == 0) a = *(const f16x8*)(tb + OFF_B1 + row * STR_B1);
  } else if constexpr (IN == 16) {
    if (g < 2) a = *(const f16x8*)(tb + OFF_B2 + row * STR_B2 + g * 16);
  } else {  // IN == 32
    a = *(const f16x8*)(tb + OFF_B3 + row * STR_B3 + g * 16);
  }
  return a;
}

DEV void writeD(char* tb, int off, int strideB, int OUT, int coltile,
                f32x4 d, int lane) {
  const int col = (lane & 15) + 16 * coltile;
  const int rb  = (lane >> 4) * 4;
  if (col < OUT) {
#pragma unroll
    for (int r = 0; r < 4; ++r) {
      *(_Float16*)(tb + off + (rb + r) * strideB + col * 2) =
          (_Float16)fmaxf(d[r], 0.0f);  // ReLU then f16 (RNE)
    }
  }
}

__global__ void __launch_bounds__(256)
mlp6_mfma(const float* __restrict__ x,
          const float* __restrict__ W1, const float* __restrict__ b1,
          const float* __restrict__ W2, const float* __restrict__ b2,
          const float* __restrict__ W3, const float* __restrict__ b3,
          const float* __restrict__ W4, const float* __restrict__ b4,
          const float* __restrict__ W5, const float* __restrict__ b5,
          const float* __restrict__ W6, const float* __restrict__ b6,
          float* __restrict__ out, int nchunks) {
  __shared__ char smem[SMEM_BYTES];
  const int lane = threadIdx.x & 63;
  const int wid  = threadIdx.x >> 6;
  char* tb[2] = { smem + (wid * 2 + 0) * TILE_BYTES,
                  smem + (wid * 2 + 1) * TILE_BYTES };

  // Weight fragments (built once, L1/L2-cached loads, ~7x4 VGPRs).
  const f16x8 B1  = build_bfrag(W1, 4, 8, 0, lane);
  const f16x8 B2  = build_bfrag(W2, 8, 16, 0, lane);
  const f16x8 B3a = build_bfrag(W3, 16, 32, 0, lane);
  const f16x8 B3b = build_bfrag(W3, 16, 32, 1, lane);
  const f16x8 B4  = build_bfrag(W4, 32, 16, 0, lane);
  const f16x8 B5  = build_bfrag(W5, 16, 8, 0, lane);
  const f16x8 B6  = build_bfrag(W6, 8, 4, 0, lane);

  // Bias as MFMA C-operand init (per-lane col value; junk cols masked at write).
  const int col = lane & 15;
  const float c1  = (col < 8) ? b1[col] : 0.0f;
  const float c2  = b2[col];
  const float c3a = b3[col];
  const float c3b = b3[col + 16];
  const float c4  = b4[col];
  const float c5  = (col < 8) ? b5[col] : 0.0f;
  const float c6  = (col < 4) ? b6[col] : 0.0f;

  const int gw = blockIdx.x * (blockDim.x >> 6) + wid;
  const int nw = gridDim.x * (blockDim.x >> 6);

  for (int chunk = gw; chunk < nchunks; chunk += nw) {
    const int rowBase = chunk * 32;

    // Stage input: 32 rows x 4 f32 = 128 floats, one float2 per lane,
    // convert to f16, write to the owning tile's input buffer.
    {
      const float2 v = *(const float2*)(x + (size_t)rowBase * 4 + lane * 2);
      const int r32 = lane >> 1;                    // 0..31
      char* t = tb[r32 >> 4];
      f16x2 h; h[0] = (_Float16)v.x; h[1] = (_Float16)v.y;
      *(f16x2*)(t + OFF_IN + (r32 & 15) * STR_IN + (lane & 1) * 4) = h;
    }

    f32x4 d[2];
    f32x4 e[2][2];

    // L1: 4 -> 8
#pragma unroll
    for (int t = 0; t < 2; ++t) {
      f16x8 a = readA<4>(tb[t], lane);
      f32x4 c = {c1, c1, c1, c1};
      d[t] = __builtin_amdgcn_mfma_f32_16x16x32_f16(a, B1, c, 0, 0, 0);
    }
#pragma unroll
    for (int t = 0; t < 2; ++t) writeD(tb[t], OFF_B1, STR_B1, 8, 0, d[t], lane);

    // L2: 8 -> 16
#pragma unroll
    for (int t = 0; t < 2; ++t) {
      f16x8 a = readA<8>(tb[t], lane);
      f32x4 c = {c2, c2, c2, c2};
      d[t] = __builtin_amdgcn_mfma_f32_16x16x32_f16(a, B2, c, 0, 0, 0);
    }
#pragma unroll
    for (int t = 0; t < 2; ++t) writeD(tb[t], OFF_B2, STR_B2, 16, 0, d[t], lane);

    // L3: 16 -> 32 (two 16-col tiles)
#pragma unroll
    for (int t = 0; t < 2; ++t) {
      f16x8 a = readA<16>(tb[t], lane);
      f32x4 ca = {c3a, c3a, c3a, c3a};
      f32x4 cb = {c3b, c3b, c3b, c3b};
      e[t][0] = __builtin_amdgcn_mfma_f32_16x16x32_f16(a, B3a, ca, 0, 0, 0);
      e[t][1] = __builtin_amdgcn_mfma_f32_16x16x32_f16(a, B3b, cb, 0, 0, 0);
    }
#pragma unroll
    for (int t = 0; t < 2; ++t) {
      writeD(tb[t], OFF_B3, STR_B3, 32, 0, e[t][0], lane);
      writeD(tb[t], OFF_B3, STR_B3, 32, 1, e[t][1], lane);
    }

    // L4: 32 -> 16 (K=32, single MFMA)
#pragma unroll
    for (int t = 0; t < 2; ++t) {
      f16x8 a = readA<32>(tb[t], lane);
      f32x4 c = {c4, c4, c4, c4};
      d[t] = __builtin_amdgcn_mfma_f32_16x16x32_f16(a, B4, c, 0, 0, 0);
    }
#pragma unroll
    for (int t = 0; t < 2; ++t) writeD(tb[t], OFF_B2, STR_B2, 16, 0, d[t], lane);

    // L5: 16 -> 8
#pragma unroll
    for (int t = 0; t < 2; ++t) {
      f16x8 a = readA<16>(tb[t], lane);
      f32x4 c = {c5, c5, c5, c5};
      d[t] = __builtin_amdgcn_mfma_f32_16x16x32_f16(a, B5, c, 0, 0, 0);
    }
#pragma unroll
    for (int t = 0; t < 2; ++t) writeD(tb[t], OFF_B1, STR_B1, 8, 0, d[t], lane);

    // L6: 8 -> 4, ReLU, store f32 to global
#pragma unroll
    for (int t = 0; t < 2; ++t) {
      f16x8 a = readA<8>(tb[t], lane);
      f32x4 c = {c6, c6, c6, c6};
      d[t] = __builtin_amdgcn_mfma_f32_16x16x32_f16(a, B6, c, 0, 0, 0);
    }
#pragma unroll
    for (int t = 0; t < 2; ++t) {
      if (col < 4) {
        const int rb = (lane >> 4) * 4;
#pragma unroll
        for (int r = 0; r < 4; ++r) {
          out[(size_t)(rowBase + t * 16 + rb + r) * 4 + col] =
              fmaxf(d[t][r], 0.0f);
        }
      }
    }
  }
}

extern "C" void kernel_launch(void* const* d_in, const int* in_sizes, int n_in,
                              void* d_out, int out_size, void* d_ws, size_t ws_size,
                              hipStream_t stream) {
  const float* x  = (const float*)d_in[0];
  const float* W1 = (const float*)d_in[1];
  const float* b1 = (const float*)d_in[2];
  const float* W2 = (const float*)d_in[3];
  const float* b2 = (const float*)d_in[4];
  const float* W3 = (const float*)d_in[5];
  const float* b3 = (const float*)d_in[6];
  const float* W4 = (const float*)d_in[7];
  const float* b4 = (const float*)d_in[8];
  const float* W5 = (const float*)d_in[9];
  const float* b5 = (const float*)d_in[10];
  const float* W6 = (const float*)d_in[11];
  const float* b6 = (const float*)d_in[12];
  float* out = (float*)d_out;

  const int nrows   = in_sizes[0] / 4;  // 4,000,000
  const int nchunks = nrows / 32;       // 125,000 (exact)

  mlp6_mfma<<<dim3(1024), dim3(256), 0, stream>>>(
      x, W1, b1, W2, b2, W3, b3, W4, b4, W5, b5, W6, b6, out, nchunks);
}

// Round 7
// 193.108 us; speedup vs baseline: 1.3534x; 1.0220x over previous
//
#include <hip/hip_runtime.h>

// MLP 4->8->16->32->16->8->4, ReLU after every layer, N=4M rows, fp32 I/O.
//
// Transposed MFMA chain: every layer computes
//   h_l^T = ReLU(W_l^T · h_{l-1}^T + b_l)   via v_mfma_f32_16x16x32_f16.
// gfx950 16x16x32 layouts (validated end-to-end by the round-3 kernel):
//   A: lane l holds A[m=l&15][k=(l>>4)*8+j], j=0..7
//   B: lane l holds B[k=(l>>4)*8+j][n=l&15]
//   D: lane l reg r holds D[m=(l>>4)*4+r][n=l&15]
// With A = W^T (m=out-col, k=in-col) and B = h^T (k=in-col, n=batch-row),
// D holds h_next^T: lane l = batch row (l&15), regs = 4 output cols.
// Inter-layer transport:
//   * 16-or-less-wide hops (L1->L2->L3, L4->L5->L6): fixed ds_bpermute pair
//     (addrA/addrB) — misroutes can only land in ZERO-WEIGHTED k-slots.
//   * L3->L4 hop (the only 32-wide one; ALL k-slots nonzero-weighted):
//     explicit per-wave LDS round-trip (round-3-validated semantics):
//     each lane writes its Da/Db packs (2x ds_write_b64), reads its L4
//     B-frag as one ds_read_b128. Same-wave program order, no barriers.
// RNE f32->f16 conversion everywhere (round-5 lesson: RTZ compounding).

typedef _Float16 f16x8 __attribute__((ext_vector_type(8)));
typedef float    f32x4 __attribute__((ext_vector_type(4)));
typedef unsigned int u32;
typedef u32 u32x2 __attribute__((ext_vector_type(2)));
typedef u32 u32x4 __attribute__((ext_vector_type(4)));

#define DEV __device__ __forceinline__

DEV u32 pk_rne(float a, float b) {
  const u32 ra = (u32)__builtin_bit_cast(unsigned short, (_Float16)a);
  const u32 rb = (u32)__builtin_bit_cast(unsigned short, (_Float16)b);
  return ra | (rb << 16);
}
DEV u32 packrelu(float a, float b) {
  return pk_rne(fmaxf(a, 0.0f), fmaxf(b, 0.0f));
}
DEV u32 bperm(int byteaddr, u32 v) {
  return (u32)__builtin_amdgcn_ds_bpermute(byteaddr, (int)v);
}
DEV f16x8 mkB(u32 a, u32 b, u32 c, u32 d) {
  u32x4 v = {a, b, c, d};
  return __builtin_bit_cast(f16x8, v);
}

// A-frag for W^T: A[m][k] = W[k][moff+m] for k<IN, m<mvalid; else 0. ld = OUT
// width of W. Built once per kernel; loads L2-cached.
DEV f16x8 wfragT(const float* __restrict__ W, int IN, int ld, int moff,
                 int mvalid, int lane) {
  const int m  = lane & 15;
  const int k0 = (lane >> 4) * 8;
  f16x8 r = {0, 0, 0, 0, 0, 0, 0, 0};
#pragma unroll
  for (int j = 0; j < 8; ++j) {
    const int k = k0 + j;
    float w = 0.0f;
    if (k < IN && m < mvalid) w = W[k * ld + moff + m];
    r[j] = (_Float16)w;   // RNE
  }
  return r;
}

// Bias as MFMA C operand: c[r] = b[off + (l>>4)*4 + r] (0 beyond nvalid).
DEV f32x4 biasC(const float* __restrict__ b, int off, int nvalid, int lane) {
  const int g = lane >> 4;
  f32x4 c;
#pragma unroll
  for (int r = 0; r < 4; ++r) {
    const int idx = g * 4 + r;
    c[r] = (idx < nvalid) ? b[off + idx] : 0.0f;
  }
  return c;
}

#define MFMA16(A, B, C) __builtin_amdgcn_mfma_f32_16x16x32_f16((A), (B), (C), 0, 0, 0)

// Per-(wave,tile) h3 staging: 16 rows x 80 B (64 B data + 16 pad), 16-aligned.
constexpr int H3_STRIDE = 80;
constexpr int H3_TILE   = 16 * H3_STRIDE;          // 1280 B
constexpr int H3_BYTES  = 4 /*waves*/ * 4 /*tiles*/ * H3_TILE;  // 20480 B

__global__ void __launch_bounds__(256)
mlp6_bperm(const float* __restrict__ x,
           const float* __restrict__ W1, const float* __restrict__ b1,
           const float* __restrict__ W2, const float* __restrict__ b2,
           const float* __restrict__ W3, const float* __restrict__ b3,
           const float* __restrict__ W4, const float* __restrict__ b4,
           const float* __restrict__ W5, const float* __restrict__ b5,
           const float* __restrict__ W6, const float* __restrict__ b6,
           float* __restrict__ out, int nchunks) {
  __shared__ __align__(16) char h3mem[H3_BYTES];
  const int lane = threadIdx.x & 63;
  const int wid  = threadIdx.x >> 6;
  const int row  = lane & 15;
  const int grp  = lane >> 4;

  // Loop-invariant weight fragments (W^T) and biases.
  const f16x8 A1  = wfragT(W1, 4, 8, 0, 8, lane);
  const f16x8 A2  = wfragT(W2, 8, 16, 0, 16, lane);
  const f16x8 A3a = wfragT(W3, 16, 32, 0, 16, lane);
  const f16x8 A3b = wfragT(W3, 16, 32, 16, 16, lane);
  const f16x8 A4  = wfragT(W4, 32, 16, 0, 16, lane);
  const f16x8 A5  = wfragT(W5, 16, 8, 0, 8, lane);
  const f16x8 A6  = wfragT(W6, 8, 4, 0, 4, lane);

  const f32x4 C1  = biasC(b1, 0, 8, lane);
  const f32x4 C2  = biasC(b2, 0, 16, lane);
  const f32x4 C3a = biasC(b3, 0, 16, lane);
  const f32x4 C3b = biasC(b3, 16, 16, lane);
  const f32x4 C4  = biasC(b4, 0, 16, lane);
  const f32x4 C5  = biasC(b5, 0, 8, lane);
  const f32x4 C6  = biasC(b6, 0, 4, lane);

  // Fixed permutation addresses (byte addrs for ds_bpermute):
  //   srcA = row + 32*(G&1), srcB = srcA + 16   (G = lane>>4; mod-64 wrap)
  const int addrA = 4 * (row + ((lane & 16) << 1));
  const int addrB = addrA + 64;

  const int gw = (int)((blockIdx.x * blockDim.x + threadIdx.x) >> 6);
  const int nw = (int)((gridDim.x * blockDim.x) >> 6);

  for (int ch = gw; ch < nchunks; ch += nw) {
    const size_t base = (size_t)ch * 64;

    // Stage: 64 rows, one float4 per lane (coalesced 16B), pack to f16 (RNE).
    const float4 xr = *reinterpret_cast<const float4*>(x + (base + lane) * 4);
    const u32 xp0 = pk_rne(xr.x, xr.y);
    const u32 xp1 = pk_rne(xr.z, xr.w);

#pragma unroll
    for (int t = 0; t < 4; ++t) {
      char* tbuf = h3mem + ((wid * 4 + t) * 16 + row) * H3_STRIDE;

      // L1 B-frag: row (l&15) of tile t -> source lane 16t + row.
      const int saddr = 4 * (t * 16 + row);
      const u32 s0 = bperm(saddr, xp0);
      const u32 s1 = bperm(saddr, xp1);
      f32x4 D = MFMA16(A1, mkB(s0, s1, s0, s0), C1);   // 4 -> 8

      // L2: 8 -> 16
      u32 p0 = packrelu(D[0], D[1]);
      u32 p1 = packrelu(D[2], D[3]);
      D = MFMA16(A2, mkB(bperm(addrA, p0), bperm(addrA, p1),
                         bperm(addrB, p0), bperm(addrB, p1)), C2);

      // L3: 16 -> 32 (two M-halves share one B-frag)
      p0 = packrelu(D[0], D[1]);
      p1 = packrelu(D[2], D[3]);
      const f16x8 B3 = mkB(bperm(addrA, p0), bperm(addrA, p1),
                           bperm(addrB, p0), bperm(addrB, p1));
      const f32x4 Da = MFMA16(A3a, B3, C3a);
      const f32x4 Db = MFMA16(A3b, B3, C3b);

      // L3 -> L4 transport via LDS (explicit, round-3-validated semantics).
      // Lane (row, G') holds h3 features {4G'..4G'+3} (Da) and
      // {16+4G'..16+4G'+3} (Db) of batch-row `row`. Write both packs:
      {
        u32x2 wa = {packrelu(Da[0], Da[1]), packrelu(Da[2], Da[3])};
        u32x2 wb = {packrelu(Db[0], Db[1]), packrelu(Db[2], Db[3])};
        *reinterpret_cast<u32x2*>(tbuf + 8 * grp)      = wa;  // bytes 8G'..8G'+7
        *reinterpret_cast<u32x2*>(tbuf + 32 + 8 * grp) = wb;  // bytes 32+8G'..
      }
      // L4 B-frag: k=8G..8G+7 of batch-row `row` = bytes 16G..16G+15.
      const f16x8 B4 = *reinterpret_cast<const f16x8*>(tbuf + 16 * grp);
      f32x4 D4 = MFMA16(A4, B4, C4);                    // 32 -> 16

      // L5: 16 -> 8
      p0 = packrelu(D4[0], D4[1]);
      p1 = packrelu(D4[2], D4[3]);
      D = MFMA16(A5, mkB(bperm(addrA, p0), bperm(addrA, p1),
                         bperm(addrB, p0), bperm(addrB, p1)), C5);

      // L6: 8 -> 4
      p0 = packrelu(D[0], D[1]);
      p1 = packrelu(D[2], D[3]);
      D = MFMA16(A6, mkB(bperm(addrA, p0), bperm(addrA, p1),
                         bperm(addrB, p0), bperm(addrB, p1)), C6);

      // Group-0 lanes hold the full f32 output row (cols 0..3 = regs 0..3).
      if ((lane & 48) == 0) {
        const float4 o = make_float4(fmaxf(D[0], 0.0f), fmaxf(D[1], 0.0f),
                                     fmaxf(D[2], 0.0f), fmaxf(D[3], 0.0f));
        *reinterpret_cast<float4*>(out + (base + t * 16 + row) * 4) = o;
      }
    }
  }
}

extern "C" void kernel_launch(void* const* d_in, const int* in_sizes, int n_in,
                              void* d_out, int out_size, void* d_ws, size_t ws_size,
                              hipStream_t stream) {
  const float* x  = (const float*)d_in[0];
  const float* W1 = (const float*)d_in[1];
  const float* b1 = (const float*)d_in[2];
  const float* W2 = (const float*)d_in[3];
  const float* b2 = (const float*)d_in[4];
  const float* W3 = (const float*)d_in[5];
  const float* b3 = (const float*)d_in[6];
  const float* W4 = (const float*)d_in[7];
  const float* b4 = (const float*)d_in[8];
  const float* W5 = (const float*)d_in[9];
  const float* b5 = (const float*)d_in[10];
  const float* W6 = (const float*)d_in[11];
  const float* b6 = (const float*)d_in[12];
  float* out = (float*)d_out;

  const int nrows   = in_sizes[0] / 4;  // 4,000,000
  const int nchunks = nrows / 64;       // 62,500 chunks of 64 rows (exact)

  mlp6_bperm<<<dim3(2048), dim3(256), 0, stream>>>(
      x, W1, b1, W2, b2, W3, b3, W4, b4, W5, b5, W6, b6, out, nchunks);
}

// Round 8
// 192.915 us; speedup vs baseline: 1.3548x; 1.0010x over previous
//
#include <hip/hip_runtime.h>

// MLP 4->8->16->32->16->8->4, ReLU after every layer, N=4M rows, fp32 I/O.
//
// v_mfma_f32_32x32x16_f16 transposed chain, 32 rows/tile, ZERO DS ops.
//   A: lane l holds A[m=l&31][k=(l>>5)*8+j], j=0..7   (assumed, analog of
//      the on-device-validated 16x16x32 layout)
//   B: lane l holds B[k=(l>>5)*8+j][col=l&31]
//   D: lane l reg r holds D[m=(r&3)+8*(r>>2)+4*(l>>5)][col=l&31]  (m74/m101
//      HW-verified, dtype-independent)
// Transposed: A=W^T (m=out-feat, k=in-feat), B=h^T (k=in-feat, col=batch row).
// D reg r at half H holds feat (r&3)+8*(r>>2)+4H of batch-row col.
//
// Inter-layer relayout entirely in-register with v_permlane32_swap_b32
// (swaps upper 32 lanes of op0 with lower 32 lanes of op1; both outputs used):
//   packs q_i = pk(D[2i],D[2i+1]); swap32(q0,q2) -> (dw0, dw2); swap32(q1,q3)
//   -> (dw1, dw3). Verified by per-lane feat bookkeeping for 8/16/32-wide hops.
// Bias: L1/L2/L6 fold b into spare k-slot (A[m][IN]=b[m], B[IN][col]=1.0);
// L3/L4/L5 (no spare k) use the MFMA C operand.
// Junk discipline: A-frags zero beyond (IN,mvalid) -> junk activations are
// EXACTLY 0 out of every MFMA; junk-tolerant B slots rely on zero weights.
// Pack: v_cvt_pkrtz (RTZ) + v_pk_max_f16 ReLU. (Round-5/6 post-mortem: the
// 3.32e-2 was a structural misroute, identical under RTZ and RNE — RTZ's own
// cost is a few e-3, inside the 8.7e-3 threshold. Watch absmax.)

typedef _Float16 f16x8 __attribute__((ext_vector_type(8)));
typedef float    f32x16 __attribute__((ext_vector_type(16)));
typedef unsigned int u32;
typedef u32 u32x4v __attribute__((ext_vector_type(4)));

#define DEV __device__ __forceinline__

DEV u32 pk(float a, float b) {          // f32x2 -> packed f16 (RTZ), no relu
  return __builtin_bit_cast(u32, __builtin_amdgcn_cvt_pkrtz(a, b));
}
DEV u32 pkr(float a, float b) {         // pack + packed ReLU
  u32 p = pk(a, b), r;
  asm("v_pk_max_f16 %0, %1, 0" : "=v"(r) : "v"(p));
  return r;
}
DEV void swap32(u32& a, u32& b) {
  // a' = [a_lo32 | b_lo32], b' = [a_hi32 | b_hi32]
  asm("v_permlane32_swap_b32 %0, %1" : "+v"(a), "+v"(b));
}
DEV f16x8 mkB(u32 a, u32 b, u32 c, u32 d) {
  u32x4v v = {a, b, c, d};
  return __builtin_bit_cast(f16x8, v);
}

// A-frag (W^T) for 32x32x16: A[m=l&31][k=(l>>5)*8+j]. Global k' = koff+k.
// w = W[k'][m] for k'<IN, m<mvalid; b[m] at k'==kbias; else 0.
DEV f16x8 wfragT32(const float* __restrict__ W, int IN, int ld, int mvalid,
                   int koff, const float* __restrict__ bias, int kbias,
                   int lane) {
  const int m  = lane & 31;
  const int k0 = (lane >> 5) * 8;
  f16x8 r = {0, 0, 0, 0, 0, 0, 0, 0};
#pragma unroll
  for (int j = 0; j < 8; ++j) {
    const int kg = koff + k0 + j;
    float w = 0.0f;
    if (m < mvalid) {
      if (kg < IN)            w = W[kg * ld + m];
      else if (bias && kg == kbias) w = bias[m];
    }
    r[j] = (_Float16)w;   // RNE for weights/bias
  }
  return r;
}

// Bias as MFMA C operand: c[r] = b[(r&3)+8*(r>>2)+4H] (0 beyond nvalid).
DEV f32x16 biasC32(const float* __restrict__ b, int nvalid, int lane) {
  const int H = lane >> 5;
  f32x16 c;
#pragma unroll
  for (int r = 0; r < 16; ++r) {
    const int m = (r & 3) + 8 * (r >> 2) + 4 * H;
    c[r] = (m < nvalid) ? b[m] : 0.0f;
  }
  return c;
}

#define MFMA32(A, B, C) __builtin_amdgcn_mfma_f32_32x32x16_f16((A), (B), (C), 0, 0, 0)

__global__ void __launch_bounds__(256)
mlp6_mfma32(const float* __restrict__ x,
            const float* __restrict__ W1, const float* __restrict__ b1,
            const float* __restrict__ W2, const float* __restrict__ b2,
            const float* __restrict__ W3, const float* __restrict__ b3,
            const float* __restrict__ W4, const float* __restrict__ b4,
            const float* __restrict__ W5, const float* __restrict__ b5,
            const float* __restrict__ W6, const float* __restrict__ b6,
            float* __restrict__ out, int nchunks) {
  const int  lane = threadIdx.x & 63;
  const bool hi32 = lane >= 32;

  // Loop-invariant weight fragments. Bias-in-k for L1 (k=4), L2 (k=8), L6 (k=8).
  const f16x8 A1  = wfragT32(W1, 4, 8, 8, 0, b1, 4, lane);
  const f16x8 A2  = wfragT32(W2, 8, 16, 16, 0, b2, 8, lane);
  const f16x8 A3  = wfragT32(W3, 16, 32, 32, 0, nullptr, -1, lane);
  const f16x8 A4a = wfragT32(W4, 32, 16, 16, 0, nullptr, -1, lane);
  const f16x8 A4b = wfragT32(W4, 32, 16, 16, 16, nullptr, -1, lane);
  const f16x8 A5  = wfragT32(W5, 16, 8, 8, 0, nullptr, -1, lane);
  const f16x8 A6  = wfragT32(W6, 8, 4, 4, 0, b6, 8, lane);

  const f32x16 C3 = biasC32(b3, 32, lane);
  const f32x16 C4 = biasC32(b4, 16, lane);
  const f32x16 C5 = biasC32(b5, 8, lane);
  const f32x16 Z  = {};                   // zero C for L1/L2/L6

  const u32 kone = 0x00003C00u;           // f16 (1.0, 0.0) — bias-row B value

  const int gw = (int)((blockIdx.x * blockDim.x + threadIdx.x) >> 6);
  const int nw = (int)((gridDim.x * blockDim.x) >> 6);

  for (int ch = gw; ch < nchunks; ch += nw) {
    const size_t base = (size_t)ch * 64;

    // 64 rows: lane L holds row base+L (coalesced float4), pack to f16 RTZ.
    const float4 xr = *reinterpret_cast<const float4*>(x + (base + lane) * 4);
    const u32 xp0 = pk(xr.x, xr.y);       // feats (0,1)  — NO relu on input
    const u32 xp1 = pk(xr.z, xr.w);       // feats (2,3)

#pragma unroll
    for (int t = 0; t < 2; ++t) {
      // ---- L1: 4 -> 8 (bias at k=4 via kone) ----
      u32 i0 = xp0, i1 = xp1;
      if (t == 1) {                       // rows 32..63 -> broadcast hi half
        u32 c0 = xp0, c1 = xp0; swap32(c0, c1);   // c1 = [xp0_hi | xp0_hi]
        u32 c2 = xp1, c3 = xp1; swap32(c2, c3);   // c3 = [xp1_hi | xp1_hi]
        i0 = c1; i1 = c3;
      }
      f32x16 D = MFMA32(A1, mkB(i0, i1, kone, kone), Z);

      // ---- hop(8) -> B2 (bias at k=8: H1 lanes' dw0 = (1.0, 0)) ----
      u32 q0 = pkr(D[0], D[1]);           // H0:(0,1)  H1:(4,5)
      u32 q1 = pkr(D[2], D[3]);           // H0:(2,3)  H1:(6,7)
      u32 c0 = q0, c1 = q0; swap32(c0, c1);   // c1 = [(4,5)|(4,5)] = dw2
      u32 c2 = q1, c3 = q1; swap32(c2, c3);   // c3 = [(6,7)|(6,7)] = dw3
      u32 dw0 = hi32 ? kone : q0;             // H1 dw0 -> bias one-hot
      D = MFMA32(A2, mkB(dw0, q1, c1, c3), Z);   // 8 -> 16

      // ---- hop(16) -> B3 ----
      q0 = pkr(D[0], D[1]); q1 = pkr(D[2], D[3]);
      u32 q2 = pkr(D[4], D[5]); u32 q3 = pkr(D[6], D[7]);
      swap32(q0, q2);                     // q0 = dw0 = [(0,1)|(8,9)], q2 = dw2
      swap32(q1, q3);                     // q1 = dw1,               q3 = dw3
      D = MFMA32(A3, mkB(q0, q1, q2, q3), C3);   // 16 -> 32 (single MFMA)

      // ---- hop(32) -> Bk0, Bk1 (two K=16 accumulating MFMAs) ----
      u32 r0 = pkr(D[0], D[1]),  r1 = pkr(D[2], D[3]);
      u32 r2 = pkr(D[4], D[5]),  r3 = pkr(D[6], D[7]);
      u32 r4 = pkr(D[8], D[9]),  r5 = pkr(D[10], D[11]);
      u32 r6 = pkr(D[12], D[13]), r7 = pkr(D[14], D[15]);
      swap32(r0, r2); swap32(r1, r3);     // Bk0: feats 0..15
      swap32(r4, r6); swap32(r5, r7);     // Bk1: feats 16..31
      D = MFMA32(A4a, mkB(r0, r1, r2, r3), C4);
      D = MFMA32(A4b, mkB(r4, r5, r6, r7), D);   // 32 -> 16

      // ---- hop(16) -> B5 ----
      q0 = pkr(D[0], D[1]); q1 = pkr(D[2], D[3]);
      q2 = pkr(D[4], D[5]); q3 = pkr(D[6], D[7]);
      swap32(q0, q2); swap32(q1, q3);
      D = MFMA32(A5, mkB(q0, q1, q2, q3), C5);   // 16 -> 8

      // ---- hop(8) -> B6 (bias at k=8) ----
      q0 = pkr(D[0], D[1]); q1 = pkr(D[2], D[3]);
      c0 = q0; c1 = q0; swap32(c0, c1);   // dw2
      c2 = q1; c3 = q1; swap32(c2, c3);   // dw3
      dw0 = hi32 ? kone : q0;
      D = MFMA32(A6, mkB(dw0, q1, c1, c3), Z);   // 8 -> 4

      // ---- store: lanes 0..31 hold feats 0..3 (regs 0..3, H=0) ----
      if (!hi32) {
        const float4 o = make_float4(fmaxf(D[0], 0.0f), fmaxf(D[1], 0.0f),
                                     fmaxf(D[2], 0.0f), fmaxf(D[3], 0.0f));
        *reinterpret_cast<float4*>(out + (base + (size_t)t * 32 + lane) * 4) = o;
      }
    }
  }
}

extern "C" void kernel_launch(void* const* d_in, const int* in_sizes, int n_in,
                              void* d_out, int out_size, void* d_ws, size_t ws_size,
                              hipStream_t stream) {
  const float* x  = (const float*)d_in[0];
  const float* W1 = (const float*)d_in[1];
  const float* b1 = (const float*)d_in[2];
  const float* W2 = (const float*)d_in[3];
  const float* b2 = (const float*)d_in[4];
  const float* W3 = (const float*)d_in[5];
  const float* b3 = (const float*)d_in[6];
  const float* W4 = (const float*)d_in[7];
  const float* b4 = (const float*)d_in[8];
  const float* W5 = (const float*)d_in[9];
  const float* b5 = (const float*)d_in[10];
  const float* W6 = (const float*)d_in[11];
  const float* b6 = (const float*)d_in[12];
  float* out = (float*)d_out;

  const int nrows   = in_sizes[0] / 4;  // 4,000,000
  const int nchunks = nrows / 64;       // 62,500 chunks of 64 rows (exact)

  mlp6_mfma32<<<dim3(2048), dim3(256), 0, stream>>>(
      x, W1, b1, W2, b2, W3, b3, W4, b4, W5, b5, W6, b6, out, nchunks);
}

// Round 9
// 166.107 us; speedup vs baseline: 1.5734x; 1.1614x over previous
//
#include <hip/hip_runtime.h>

// MLP 4->8->16->32->16->8->4, ReLU after every layer, N=4M rows, fp32 I/O.
//
// v_mfma_f32_32x32x16_f16 transposed chain, TWO independent 32-row tile
// chains per wave iteration, explicitly interleaved stage-by-stage so chain1
// VALU hides chain0 MFMA latency (round-8 post-mortem: compiler serialized
// the unrolled t-loop -> latency-bound at 91us with both pipes <45%).
//
// Layouts (ALL HW-validated by round-8 pass at absmax floor):
//   A: lane l holds A[m=l&31][k=(l>>5)*8+j]
//   B: lane l holds B[k=(l>>5)*8+j][col=l&31]
//   D: lane l reg r holds D[m=(r&3)+8*(r>>2)+4*(l>>5)][col=l&31]
// Relayout via v_permlane32_swap_b32 (a'=[a_lo|b_lo], b'=[a_hi|b_hi]).
// Bias: L1/L2/L6 in spare k-slot (B=1.0 one-hot); L3/L4/L5 as packed-f16
// v_pk_add_f16 at the pack sites (frees 48 VGPRs of f32x16 C operands ->
// keeps the 2-chain schedule under the 128-VGPR occupancy cliff).

typedef _Float16 f16x8 __attribute__((ext_vector_type(8)));
typedef float    f32x16 __attribute__((ext_vector_type(16)));
typedef unsigned int u32;
typedef u32 u32x4v __attribute__((ext_vector_type(4)));

#define DEV __device__ __forceinline__

DEV u32 pk(float a, float b) {          // f32x2 -> packed f16 (RTZ)
  return __builtin_bit_cast(u32, __builtin_amdgcn_cvt_pkrtz(a, b));
}
DEV u32 pk_rne(float a, float b) {      // RNE pack (bias build, once)
  const u32 ra = (u32)__builtin_bit_cast(unsigned short, (_Float16)a);
  const u32 rb = (u32)__builtin_bit_cast(unsigned short, (_Float16)b);
  return ra | (rb << 16);
}
DEV u32 pkmax0(u32 p) {                 // packed ReLU
  u32 r;
  asm("v_pk_max_f16 %0, %1, 0" : "=v"(r) : "v"(p));
  return r;
}
DEV u32 pkadd(u32 a, u32 b) {
  u32 r;
  asm("v_pk_add_f16 %0, %1, %2" : "=v"(r) : "v"(a), "v"(b));
  return r;
}
DEV u32 pkr(float a, float b) {         // pack + ReLU (no bias)
  return pkmax0(pk(a, b));
}
DEV u32 pkrb(float a, float b, u32 pbias) {  // pack + bias + ReLU
  return pkmax0(pkadd(pk(a, b), pbias));
}
DEV void swap32(u32& a, u32& b) {
  asm("v_permlane32_swap_b32 %0, %1" : "+v"(a), "+v"(b));
}
DEV f16x8 mkB(u32 a, u32 b, u32 c, u32 d) {
  u32x4v v = {a, b, c, d};
  return __builtin_bit_cast(f16x8, v);
}

// A-frag (W^T): A[m=l&31][k=(l>>5)*8+j]; W[kg][m] for kg<IN, m<mvalid;
// bias[m] at kg==kbias; else 0.
DEV f16x8 wfragT32(const float* __restrict__ W, int IN, int ld, int mvalid,
                   int koff, const float* __restrict__ bias, int kbias,
                   int lane) {
  const int m  = lane & 31;
  const int k0 = (lane >> 5) * 8;
  f16x8 r = {0, 0, 0, 0, 0, 0, 0, 0};
#pragma unroll
  for (int j = 0; j < 8; ++j) {
    const int kg = koff + k0 + j;
    float w = 0.0f;
    if (m < mvalid) {
      if (kg < IN)                  w = W[kg * ld + m];
      else if (bias && kg == kbias) w = bias[m];
    }
    r[j] = (_Float16)w;
  }
  return r;
}

#define MFMA32(A, B, C) __builtin_amdgcn_mfma_f32_32x32x16_f16((A), (B), (C), 0, 0, 0)

__global__ void __launch_bounds__(256)
mlp6_ilv(const float* __restrict__ x,
         const float* __restrict__ W1, const float* __restrict__ b1,
         const float* __restrict__ W2, const float* __restrict__ b2,
         const float* __restrict__ W3, const float* __restrict__ b3,
         const float* __restrict__ W4, const float* __restrict__ b4,
         const float* __restrict__ W5, const float* __restrict__ b5,
         const float* __restrict__ W6, const float* __restrict__ b6,
         float* __restrict__ out, int nchunks) {
  const int  lane = threadIdx.x & 63;
  const bool hi32 = lane >= 32;
  const int  H    = lane >> 5;

  // Loop-invariant weight fragments. Bias-in-k: L1 (k=4), L2 (k=8), L6 (k=8).
  const f16x8 A1  = wfragT32(W1, 4, 8, 8, 0, b1, 4, lane);
  const f16x8 A2  = wfragT32(W2, 8, 16, 16, 0, b2, 8, lane);
  const f16x8 A3  = wfragT32(W3, 16, 32, 32, 0, nullptr, -1, lane);
  const f16x8 A4a = wfragT32(W4, 32, 16, 16, 0, nullptr, -1, lane);
  const f16x8 A4b = wfragT32(W4, 32, 16, 16, 16, nullptr, -1, lane);
  const f16x8 A5  = wfragT32(W5, 16, 8, 8, 0, nullptr, -1, lane);
  const f16x8 A6  = wfragT32(W6, 8, 4, 4, 0, b6, 8, lane);

  // Packed-f16 biases for L3/L4/L5, matching pack-pair m-indices:
  // pack i covers D regs (2i,2i+1) -> feats m=( (2i)&3 )+8*((2i)>>2)+4H, +1.
  u32 pb3[8], pb4[4], pb5[2];
#pragma unroll
  for (int i = 0; i < 8; ++i) {
    const int m0 = ((2 * i) & 3) + 8 * ((2 * i) >> 2) + 4 * H;
    pb3[i] = pk_rne(b3[m0], b3[m0 + 1]);
  }
#pragma unroll
  for (int i = 0; i < 4; ++i) {
    const int m0 = ((2 * i) & 3) + 8 * ((2 * i) >> 2) + 4 * H;
    pb4[i] = pk_rne(b4[m0], b4[m0 + 1]);
  }
#pragma unroll
  for (int i = 0; i < 2; ++i) {
    const int m0 = ((2 * i) & 3) + 4 * H;
    pb5[i] = pk_rne(b5[m0], b5[m0 + 1]);
  }

  const f32x16 Z = {};
  const u32 kone = 0x00003C00u;           // f16 (1.0, 0.0) — bias-row value

  const int gw = (int)((blockIdx.x * blockDim.x + threadIdx.x) >> 6);
  const int nw = (int)((gridDim.x * blockDim.x) >> 6);

  if (gw >= nchunks) return;

  // Software-pipelined input load: xr holds chunk `ch`'s row block.
  float4 xr = *reinterpret_cast<const float4*>(x + ((size_t)gw * 64 + lane) * 4);

  for (int ch = gw; ch < nchunks; ch += nw) {
    const size_t base = (size_t)ch * 64;
    const int nxt = (ch + nw < nchunks) ? ch + nw : ch;
    const float4 xn =
        *reinterpret_cast<const float4*>(x + ((size_t)nxt * 64 + lane) * 4);

    const u32 xp0 = pk(xr.x, xr.y);
    const u32 xp1 = pk(xr.z, xr.w);

    // Broadcast split: one swap pair yields BOTH tiles' B dwords.
    u32 i00 = xp0, i10 = xp0; swap32(i00, i10);  // i00=[lo|lo] t0, i10=[hi|hi] t1
    u32 i01 = xp1, i11 = xp1; swap32(i01, i11);

    // ---- L1: 4 -> 8 (bias k=4) ----
    f32x16 D0 = MFMA32(A1, mkB(i00, i01, kone, kone), Z);
    f32x16 D1 = MFMA32(A1, mkB(i10, i11, kone, kone), Z);

    // ---- hop(8) -> L2: 8 -> 16 (bias k=8) ----
    {
      u32 q0 = pkr(D0[0], D0[1]), q1 = pkr(D0[2], D0[3]);
      u32 c0 = q0, c1 = q0; swap32(c0, c1);
      u32 c2 = q1, c3 = q1; swap32(c2, c3);
      D0 = MFMA32(A2, mkB(hi32 ? kone : q0, q1, c1, c3), Z);
    }
    {
      u32 q0 = pkr(D1[0], D1[1]), q1 = pkr(D1[2], D1[3]);
      u32 c0 = q0, c1 = q0; swap32(c0, c1);
      u32 c2 = q1, c3 = q1; swap32(c2, c3);
      D1 = MFMA32(A2, mkB(hi32 ? kone : q0, q1, c1, c3), Z);
    }

    // ---- hop(16) -> L3: 16 -> 32 (bias deferred to pack) ----
    {
      u32 q0 = pkr(D0[0], D0[1]), q1 = pkr(D0[2], D0[3]);
      u32 q2 = pkr(D0[4], D0[5]), q3 = pkr(D0[6], D0[7]);
      swap32(q0, q2); swap32(q1, q3);
      D0 = MFMA32(A3, mkB(q0, q1, q2, q3), Z);
    }
    {
      u32 q0 = pkr(D1[0], D1[1]), q1 = pkr(D1[2], D1[3]);
      u32 q2 = pkr(D1[4], D1[5]), q3 = pkr(D1[6], D1[7]);
      swap32(q0, q2); swap32(q1, q3);
      D1 = MFMA32(A3, mkB(q0, q1, q2, q3), Z);
    }

    // ---- hop(32) -> L4: 32 -> 16 (pb3 bias+relu; two accumulating MFMAs) ----
    {
      u32 r0 = pkrb(D0[0], D0[1], pb3[0]),  r1 = pkrb(D0[2], D0[3], pb3[1]);
      u32 r2 = pkrb(D0[4], D0[5], pb3[2]),  r3 = pkrb(D0[6], D0[7], pb3[3]);
      u32 r4 = pkrb(D0[8], D0[9], pb3[4]),  r5 = pkrb(D0[10], D0[11], pb3[5]);
      u32 r6 = pkrb(D0[12], D0[13], pb3[6]), r7 = pkrb(D0[14], D0[15], pb3[7]);
      swap32(r0, r2); swap32(r1, r3);
      swap32(r4, r6); swap32(r5, r7);
      D0 = MFMA32(A4a, mkB(r0, r1, r2, r3), Z);
      D0 = MFMA32(A4b, mkB(r4, r5, r6, r7), D0);
    }
    {
      u32 r0 = pkrb(D1[0], D1[1], pb3[0]),  r1 = pkrb(D1[2], D1[3], pb3[1]);
      u32 r2 = pkrb(D1[4], D1[5], pb3[2]),  r3 = pkrb(D1[6], D1[7], pb3[3]);
      u32 r4 = pkrb(D1[8], D1[9], pb3[4]),  r5 = pkrb(D1[10], D1[11], pb3[5]);
      u32 r6 = pkrb(D1[12], D1[13], pb3[6]), r7 = pkrb(D1[14], D1[15], pb3[7]);
      swap32(r0, r2); swap32(r1, r3);
      swap32(r4, r6); swap32(r5, r7);
      D1 = MFMA32(A4a, mkB(r0, r1, r2, r3), Z);
      D1 = MFMA32(A4b, mkB(r4, r5, r6, r7), D1);
    }

    // ---- hop(16) -> L5: 16 -> 8 (pb4) ----
    {
      u32 q0 = pkrb(D0[0], D0[1], pb4[0]), q1 = pkrb(D0[2], D0[3], pb4[1]);
      u32 q2 = pkrb(D0[4], D0[5], pb4[2]), q3 = pkrb(D0[6], D0[7], pb4[3]);
      swap32(q0, q2); swap32(q1, q3);
      D0 = MFMA32(A5, mkB(q0, q1, q2, q3), Z);
    }
    {
      u32 q0 = pkrb(D1[0], D1[1], pb4[0]), q1 = pkrb(D1[2], D1[3], pb4[1]);
      u32 q2 = pkrb(D1[4], D1[5], pb4[2]), q3 = pkrb(D1[6], D1[7], pb4[3]);
      swap32(q0, q2); swap32(q1, q3);
      D1 = MFMA32(A5, mkB(q0, q1, q2, q3), Z);
    }

    // ---- hop(8) -> L6: 8 -> 4 (pb5; bias k=8) ----
    {
      u32 q0 = pkrb(D0[0], D0[1], pb5[0]), q1 = pkrb(D0[2], D0[3], pb5[1]);
      u32 c0 = q0, c1 = q0; swap32(c0, c1);
      u32 c2 = q1, c3 = q1; swap32(c2, c3);
      D0 = MFMA32(A6, mkB(hi32 ? kone : q0, q1, c1, c3), Z);
    }
    {
      u32 q0 = pkrb(D1[0], D1[1], pb5[0]), q1 = pkrb(D1[2], D1[3], pb5[1]);
      u32 c0 = q0, c1 = q0; swap32(c0, c1);
      u32 c2 = q1, c3 = q1; swap32(c2, c3);
      D1 = MFMA32(A6, mkB(hi32 ? kone : q0, q1, c1, c3), Z);
    }

    // ---- store: lanes 0..31 hold feats 0..3 in regs 0..3 (H=0) ----
    if (!hi32) {
      const float4 o0 = make_float4(fmaxf(D0[0], 0.0f), fmaxf(D0[1], 0.0f),
                                    fmaxf(D0[2], 0.0f), fmaxf(D0[3], 0.0f));
      *reinterpret_cast<float4*>(out + (base + lane) * 4) = o0;
      const float4 o1 = make_float4(fmaxf(D1[0], 0.0f), fmaxf(D1[1], 0.0f),
                                    fmaxf(D1[2], 0.0f), fmaxf(D1[3], 0.0f));
      *reinterpret_cast<float4*>(out + (base + 32 + lane) * 4) = o1;
    }

    xr = xn;
  }
}

extern "C" void kernel_launch(void* const* d_in, const int* in_sizes, int n_in,
                              void* d_out, int out_size, void* d_ws, size_t ws_size,
                              hipStream_t stream) {
  const float* x  = (const float*)d_in[0];
  const float* W1 = (const float*)d_in[1];
  const float* b1 = (const float*)d_in[2];
  const float* W2 = (const float*)d_in[3];
  const float* b2 = (const float*)d_in[4];
  const float* W3 = (const float*)d_in[5];
  const float* b3 = (const float*)d_in[6];
  const float* W4 = (const float*)d_in[7];
  const float* b4 = (const float*)d_in[8];
  const float* W5 = (const float*)d_in[9];
  const float* b5 = (const float*)d_in[10];
  const float* W6 = (const float*)d_in[11];
  const float* b6 = (const float*)d_in[12];
  float* out = (float*)d_out;

  const int nrows   = in_sizes[0] / 4;  // 4,000,000
  const int nchunks = nrows / 64;       // 62,500 chunks of 64 rows (exact)

  // 1024 blocks = 4096 waves: ~exactly resident at 4 waves/SIMD, ~15 iters
  // each -> small tail imbalance.
  mlp6_ilv<<<dim3(1024), dim3(256), 0, stream>>>(
      x, W1, b1, W2, b2, W3, b3, W4, b4, W5, b5, W6, b6, out, nchunks);
}